// Round 1
// 1629.953 us; speedup vs baseline: 1.8004x; 1.8004x over previous
//
#include <hip/hip_runtime.h>

typedef unsigned short u16;
typedef unsigned int   u32;

typedef __attribute__((ext_vector_type(8))) __bf16 bf16x8;
typedef __attribute__((ext_vector_type(4))) float  f32x4;

// ---------- scalar/vec conversion helpers ----------
__device__ __forceinline__ float bf2f(u16 v) {
    return __uint_as_float(((u32)v) << 16);
}
__device__ __forceinline__ u16 f2bf(float f) {
    u32 u = __float_as_uint(f);
    u32 r = (u + 0x7fffu + ((u >> 16) & 1u)) >> 16;  // round-to-nearest-even
    return (u16)r;
}
__device__ __forceinline__ void unpack8(uint4 u, float* f) {
    f[0] = __uint_as_float(u.x << 16); f[1] = __uint_as_float(u.x & 0xffff0000u);
    f[2] = __uint_as_float(u.y << 16); f[3] = __uint_as_float(u.y & 0xffff0000u);
    f[4] = __uint_as_float(u.z << 16); f[5] = __uint_as_float(u.z & 0xffff0000u);
    f[6] = __uint_as_float(u.w << 16); f[7] = __uint_as_float(u.w & 0xffff0000u);
}
// 16 contiguous elements -> float[16], overloaded on storage type
__device__ __forceinline__ void load16(const u16* p, float* f) {
    unpack8(*(const uint4*)p, f);
    unpack8(*(const uint4*)(p + 8), f + 8);
}
__device__ __forceinline__ void load16(const float* p, float* f) {
    const float4* q = (const float4*)p;
    float4 a = q[0], b = q[1], c = q[2], d = q[3];
    f[0]=a.x; f[1]=a.y; f[2]=a.z; f[3]=a.w;
    f[4]=b.x; f[5]=b.y; f[6]=b.z; f[7]=b.w;
    f[8]=c.x; f[9]=c.y; f[10]=c.z; f[11]=c.w;
    f[12]=d.x; f[13]=d.y; f[14]=d.z; f[15]=d.w;
}
__device__ __forceinline__ float ld1(const u16* p)   { return bf2f(*p); }
__device__ __forceinline__ float ld1(const float* p) { return *p; }

// ---------- problem constants ----------
#define BB 4
#define NTOK 2048
#define NATOM 16384
#define CTOK 384
#define CA 128
#define NQ 32
#define NK 128
#define NH 4
#define DH 32
#define NWIN 512
#define PAD 48

// =====================================================================
// dtype detector: look at low u16 of 1024 words of W_a.
// flag = 1 (bf16 inputs) or 0 (f32 inputs)
// =====================================================================
__global__ __launch_bounds__(256) void detect_kernel(const u32* __restrict__ wa,
                                                     int* __restrict__ flag)
{
    __shared__ int cnt;
    if (threadIdx.x == 0) cnt = 0;
    __syncthreads();
    int local = 0;
#pragma unroll
    for (int i = 0; i < 4; i++) {
        u32 w = wa[threadIdx.x * 4 + i];
        u32 e = (w >> 7) & 0xFFu;   // exponent field of the LOW u16 as bf16
        if (e >= 95u && e <= 135u) local++;
    }
    atomicAdd(&cnt, local);
    __syncthreads();
    if (threadIdx.x == 0) *flag = (cnt >= 614) ? 1 : 0;
}

// =====================================================================
// Generic GEMM: C[*, ccol..+127] (+)= op(A[*, :K] @ W[:, wcol..+127])
// Tile 128x128, 256 threads, 8x8 accum per thread. K % 32 == 0.
// =====================================================================
#define GKC 32
#define GLDS 132

template<typename TA, typename TW, bool OUT_BF16, bool ADD, bool RELU>
__global__ __launch_bounds__(256) void gemm128(
    const int* __restrict__ flag, int want,
    const TA* __restrict__ A, int lda,
    const TW* __restrict__ W, int ldw, int wc0,
    void* __restrict__ Cv, int ldc, int cc0,
    int K)
{
    if (*flag != want) return;
    __shared__ float As[GKC][GLDS];   // [k][m]
    __shared__ float Ws[GKC][GLDS];   // [k][n]
    const int tid  = threadIdx.x;
    const int row0 = blockIdx.x * 128;
    const int cch  = blockIdx.y * 128;
    const int wcol = wc0 + cch;
    const int ccol = cc0 + cch;
    const int ty = tid >> 4, tx = tid & 15;

    float acc[8][8];
#pragma unroll
    for (int i = 0; i < 8; i++)
#pragma unroll
        for (int j = 0; j < 8; j++) acc[i][j] = 0.f;

    const int m_l = tid >> 1;          // 0..127
    const int ak0 = (tid & 1) << 4;    // 0 / 16
    const int w_k = tid >> 3;          // 0..31
    const int wcc = (tid & 7) << 4;    // 0..112

    for (int kc = 0; kc < K; kc += GKC) {
        float av16[16], wv16[16];
        load16(A + (size_t)(row0 + m_l) * lda + kc + ak0, av16);
        load16(W + (size_t)(kc + w_k) * ldw + wcol + wcc, wv16);
        __syncthreads();   // previous iteration's compute done
#pragma unroll
        for (int j = 0; j < 16; j++) As[ak0 + j][m_l] = av16[j];
#pragma unroll
        for (int j = 0; j < 16; j++) Ws[w_k][wcc + j] = wv16[j];
        __syncthreads();

        for (int k = 0; k < GKC; k++) {
            const float4 a0 = *(const float4*)&As[k][ty << 3];
            const float4 a1 = *(const float4*)&As[k][(ty << 3) + 4];
            const float4 w0 = *(const float4*)&Ws[k][tx << 3];
            const float4 w1 = *(const float4*)&Ws[k][(tx << 3) + 4];
            const float a[8]  = {a0.x, a0.y, a0.z, a0.w, a1.x, a1.y, a1.z, a1.w};
            const float wv[8] = {w0.x, w0.y, w0.z, w0.w, w1.x, w1.y, w1.z, w1.w};
#pragma unroll
            for (int i = 0; i < 8; i++)
#pragma unroll
                for (int j = 0; j < 8; j++)
                    acc[i][j] = fmaf(a[i], wv[j], acc[i][j]);
        }
    }

#pragma unroll
    for (int i = 0; i < 8; i++) {
        const size_t r = (size_t)row0 + (ty << 3) + i;
        if (OUT_BF16) {
            union { u16 s[8]; uint4 v; } pk;
#pragma unroll
            for (int j = 0; j < 8; j++) {
                float v = acc[i][j];
                if (RELU) v = fmaxf(v, 0.f);
                pk.s[j] = f2bf(v);
            }
            *(uint4*)((u16*)Cv + r * ldc + ccol + (tx << 3)) = pk.v;
        } else {
            float* C = (float*)Cv + r * ldc + ccol + (tx << 3);
            float4 c0, c1;
            if (ADD) { c0 = ((const float4*)C)[0]; c1 = ((const float4*)C)[1]; }
            else     { c0 = make_float4(0,0,0,0);  c1 = make_float4(0,0,0,0); }
            c0.x += acc[i][0]; c0.y += acc[i][1]; c0.z += acc[i][2]; c0.w += acc[i][3];
            c1.x += acc[i][4]; c1.y += acc[i][5]; c1.z += acc[i][6]; c1.w += acc[i][7];
            ((float4*)C)[0] = c0; ((float4*)C)[1] = c1;
        }
    }
}

// =====================================================================
// Gather: x[b,n,:] = a_tok[b, idx[b,n], :]   (f32 -> f32)
// =====================================================================
__global__ __launch_bounds__(256) void gather_kernel(
    const int* __restrict__ flag, int want,
    const float* __restrict__ a_tok, const int* __restrict__ idx,
    float* __restrict__ x)
{
    if (*flag != want) return;
    const size_t i = (size_t)blockIdx.x * 256 + threadIdx.x;  // B*N*128 total
    const int c = (int)(i & 127);
    const size_t an = i >> 7;
    const int b = (int)(an >> 14);
    const int n = (int)(an & (NATOM - 1));
    const int t = idx[b * NATOM + n];
    x[i] = a_tok[(((size_t)b * NTOK) + t) * CA + c];
}

// =====================================================================
// LayerNorm: h = (x-m)*rsqrt(var+1e-5)*g + b   (f32 in, bf16 out)
// =====================================================================
template<typename TW>
__global__ __launch_bounds__(256) void ln_kernel(
    const int* __restrict__ flag, int want,
    const float* __restrict__ x, const TW* __restrict__ g,
    const TW* __restrict__ b, u16* __restrict__ h)
{
    if (*flag != want) return;
    const int lane = threadIdx.x & 63;
    const int wv   = threadIdx.x >> 6;
    const size_t atom = (size_t)blockIdx.x * 4 + wv;
    const float* xr = x + atom * CA;
    const float v0 = xr[lane], v1 = xr[lane + 64];
    float s  = v0 + v1;
    float sq = v0 * v0 + v1 * v1;
#pragma unroll
    for (int off = 32; off > 0; off >>= 1) {
        s  += __shfl_xor(s,  off, 64);
        sq += __shfl_xor(sq, off, 64);
    }
    const float mean = s * 0.0078125f;
    const float var  = sq * 0.0078125f - mean * mean;
    const float inv  = rsqrtf(var + 1e-5f);
    u16* hr = h + atom * CA;
    hr[lane]      = f2bf((v0 - mean) * inv * ld1(g + lane)      + ld1(b + lane));
    hr[lane + 64] = f2bf((v1 - mean) * inv * ld1(g + lane + 64) + ld1(b + lane + 64));
}

// =====================================================================
// Bias: t[b,a,h] for a < 128 from the pair-MLP; single block, 512 threads
// =====================================================================
template<typename TW>
__global__ __launch_bounds__(512) void bias_kernel(
    const int* __restrict__ flag, int want,
    const float* __restrict__ x,
    const TW* __restrict__ Wcl, const TW* __restrict__ Wcm,
    const TW* __restrict__ Wm1, const TW* __restrict__ Wm2,
    const TW* __restrict__ Wpb, float* __restrict__ tb)
{
    if (*flag != want) return;
    __shared__ float Wsum[128][16];
    __shared__ float M1[16][16];
    __shared__ float M2[16][16];
    __shared__ float Pb[16][4];
    const int tid = threadIdx.x;
    for (int i = tid; i < 128 * 16; i += 512)
        Wsum[i >> 4][i & 15] = ld1(Wcl + i) + ld1(Wcm + i);
    if (tid < 256) M1[tid >> 4][tid & 15] = ld1(Wm1 + tid);
    if (tid >= 256 && tid < 512) { int t2 = tid - 256; M2[t2 >> 4][t2 & 15] = ld1(Wm2 + t2); }
    if (tid < 64) Pb[tid >> 2][tid & 3] = ld1(Wpb + tid);
    __syncthreads();

    const int b = tid >> 7, a = tid & 127;
    const float* xa = x + ((size_t)b * NATOM + a) * CA;
    float u[16];
#pragma unroll
    for (int p = 0; p < 16; p++) u[p] = 0.f;
    for (int c = 0; c < 128; c++) {
        const float xv = xa[c];
#pragma unroll
        for (int p = 0; p < 16; p++) u[p] = fmaf(xv, Wsum[c][p], u[p]);
    }
    float r1[16];
#pragma unroll
    for (int p = 0; p < 16; p++) r1[p] = 0.f;
    for (int c = 0; c < 16; c++) {
        const float rv = fmaxf(u[c], 0.f);
#pragma unroll
        for (int p = 0; p < 16; p++) r1[p] = fmaf(rv, M1[c][p], r1[p]);
    }
    float r2[16];
#pragma unroll
    for (int p = 0; p < 16; p++) r2[p] = 0.f;
    for (int c = 0; c < 16; c++) {
        const float rv = fmaxf(r1[c], 0.f);
#pragma unroll
        for (int p = 0; p < 16; p++) r2[p] = fmaf(rv, M2[c][p], r2[p]);
    }
#pragma unroll
    for (int hh = 0; hh < 4; hh++) {
        float s = 0.f;
#pragma unroll
        for (int p = 0; p < 16; p++) s = fmaf(r2[p], Pb[p][hh], s);
        tb[(size_t)tid * 4 + hh] = s;
    }
}

// =====================================================================
// Windowed attention via MFMA: one block per (b, w); one wave per head.
//
// Fragment layout assumptions for v_mfma_f32_16x16x32_bf16 (gfx950):
//   A: row = lane&15,  k = (lane>>4)*8 + i   (8 contiguous k per lane)
//   B: col = lane&15,  k = (lane>>4)*8 + i
//   C/D: col = lane&15, row = (lane>>4)*4 + reg   (HW-verified, learn_hip m89)
//
// QK^T: A = Q rows, B = K rows (direct global bf16x8 loads).
// Softmax fully in registers (row reduce = 8 local + shfl_xor 1/2/4/8).
// PV: P (bf16) round-trips per-wave through LDS in two j-halves;
//     V^T staged once per block in LDS (invalid rows zeroed -> no NaN).
// Edge K reads may touch adjacent workspace buffers; those columns are
// masked by ASSIGNING -1e9, so garbage never propagates.
// =====================================================================
#define VTP 132   // V^T row stride in u16 (264B: b64-aligned, conflict-free)
#define PPS 68    // P row stride in u16 (136B: b64-aligned, conflict-free)

__global__ __launch_bounds__(256) void attn_kernel(
    const int* __restrict__ flag, int want,
    const u16* __restrict__ qg, const u16* __restrict__ kg,
    const u16* __restrict__ vg, const float* __restrict__ tb,
    u16* __restrict__ og)
{
    if (*flag != want) return;
    __shared__ __align__(16) u16 VT[128][VTP];    // V^T: [d][j]   (33792 B)
    __shared__ __align__(16) u16 Pl[NH][32][PPS]; // per-head P half (17408 B)

    const int tid  = threadIdx.x;
    const int lane = tid & 63;
    const int h    = tid >> 6;             // wave id == head
    const int b    = blockIdx.x >> 9;
    const int w    = blockIdx.x & (NWIN - 1);
    const int row0 = w * NQ;
    const int kbase = row0 - PAD;          // first key atom (may be < 0)
    const int l15 = lane & 15;
    const int lg  = lane >> 4;

    // ---- stage V^T into LDS (all 256 threads; zero invalid rows) ----
    {
        const int j  = tid & 127;
        const int d0 = (tid >> 7) << 6;    // 0 or 64
        const int ga = kbase + j;
        const bool val = (ga >= 0) && (ga < NATOM);
        const u16* vrow = vg + ((long long)b * NATOM + ga) * CA + d0;
#pragma unroll
        for (int t2 = 0; t2 < 8; t2++) {
            union { uint4 q; u16 s[8]; } u;
            if (val) u.q = *(const uint4*)(vrow + t2 * 8);
            else     u.q = make_uint4(0u, 0u, 0u, 0u);
#pragma unroll
            for (int e = 0; e < 8; e++) VT[d0 + t2 * 8 + e][j] = u.s[e];
        }
    }

    // ---- QK^T: S[32][128] per head, 16 MFMAs, frags direct from global ----
    const long long qoff = ((long long)b * NATOM + row0) * CA + h * DH;
    const long long koff = ((long long)b * NATOM + kbase) * CA + h * DH;
    bf16x8 aq0 = *(const bf16x8*)(qg + qoff + (long long)l15 * CA + lg * 8);
    bf16x8 aq1 = *(const bf16x8*)(qg + qoff + (long long)(l15 + 16) * CA + lg * 8);

    f32x4 acc[2][8];
    {
        f32x4 z = {0.f, 0.f, 0.f, 0.f};
#pragma unroll
        for (int m = 0; m < 2; m++)
#pragma unroll
            for (int n = 0; n < 8; n++) acc[m][n] = z;
    }
#pragma unroll
    for (int n = 0; n < 8; n++) {
        bf16x8 bk = *(const bf16x8*)(kg + koff + (long long)(n * 16 + l15) * CA + lg * 8);
        acc[0][n] = __builtin_amdgcn_mfma_f32_16x16x32_bf16(aq0, bk, acc[0][n], 0, 0, 0);
        acc[1][n] = __builtin_amdgcn_mfma_f32_16x16x32_bf16(aq1, bk, acc[1][n], 0, 0, 0);
    }

    // ---- bias + scale + mask ----
    const float scale = 0.17677669529663687f;  // 1/sqrt(32)
    float tj[8], ti[2][4];
#pragma unroll
    for (int n = 0; n < 8; n++)
        tj[n] = tb[((size_t)b * 128 + n * 16 + l15) * 4 + h];
#pragma unroll
    for (int m = 0; m < 2; m++)
#pragma unroll
        for (int r = 0; r < 4; r++)
            ti[m][r] = tb[((size_t)b * 128 + m * 16 + lg * 4 + r) * 4 + h];

#pragma unroll
    for (int n = 0; n < 8; n++) {
        const int ga = kbase + n * 16 + l15;
        const bool val = (ga >= 0) && (ga < NATOM);
#pragma unroll
        for (int m = 0; m < 2; m++)
#pragma unroll
            for (int r = 0; r < 4; r++) {
                const float s = acc[m][n][r] * scale + ti[m][r] + tj[n];
                acc[m][n][r] = val ? s : -1e9f;
            }
    }

    // ---- softmax: per-row max/sum (j across l15 lanes x 8 reg tiles) ----
    float mx[2][4], inv[2][4];
#pragma unroll
    for (int m = 0; m < 2; m++)
#pragma unroll
        for (int r = 0; r < 4; r++) {
            float v = acc[m][0][r];
#pragma unroll
            for (int n = 1; n < 8; n++) v = fmaxf(v, acc[m][n][r]);
            v = fmaxf(v, __shfl_xor(v, 1, 64));
            v = fmaxf(v, __shfl_xor(v, 2, 64));
            v = fmaxf(v, __shfl_xor(v, 4, 64));
            v = fmaxf(v, __shfl_xor(v, 8, 64));
            mx[m][r] = v;
        }
#pragma unroll
    for (int m = 0; m < 2; m++)
#pragma unroll
        for (int n = 0; n < 8; n++)
#pragma unroll
            for (int r = 0; r < 4; r++)
                acc[m][n][r] = __expf(acc[m][n][r] - mx[m][r]);
#pragma unroll
    for (int m = 0; m < 2; m++)
#pragma unroll
        for (int r = 0; r < 4; r++) {
            float v = 0.f;
#pragma unroll
            for (int n = 0; n < 8; n++) v += acc[m][n][r];
            v += __shfl_xor(v, 1, 64);
            v += __shfl_xor(v, 2, 64);
            v += __shfl_xor(v, 4, 64);
            v += __shfl_xor(v, 8, 64);
            inv[m][r] = 1.0f / v;
        }

    __syncthreads();   // V^T staged

    // ---- PV: O[32][32] per head; P via per-wave LDS, two j-halves ----
    f32x4 o[2][2];
    {
        f32x4 z = {0.f, 0.f, 0.f, 0.f};
        o[0][0] = z; o[0][1] = z; o[1][0] = z; o[1][1] = z;
    }
    union B8 { bf16x8 v; uint2 u[2]; };
#pragma unroll
    for (int half = 0; half < 2; half++) {
        // drain this wave's prior Pl reads before overwrite (WAR, half 1)
        asm volatile("s_waitcnt lgkmcnt(0)" ::: "memory");
#pragma unroll
        for (int m = 0; m < 2; m++)
#pragma unroll
            for (int nn = 0; nn < 4; nn++)
#pragma unroll
                for (int r = 0; r < 4; r++)
                    Pl[h][m * 16 + lg * 4 + r][nn * 16 + l15]
                        = f2bf(acc[m][half * 4 + nn][r]);
        // make P writes visible to this wave's reads (RAW)
        asm volatile("s_waitcnt lgkmcnt(0)" ::: "memory");
#pragma unroll
        for (int ks2 = 0; ks2 < 2; ks2++) {
            const int jo = ks2 * 32 + lg * 8;        // col in P half buffer
            const int jg = half * 64 + jo;           // col in V^T (global j)
            B8 pa0, pa1, vb0, vb1;
            pa0.u[0] = *(const uint2*)&Pl[h][l15][jo];
            pa0.u[1] = *(const uint2*)&Pl[h][l15][jo + 4];
            pa1.u[0] = *(const uint2*)&Pl[h][l15 + 16][jo];
            pa1.u[1] = *(const uint2*)&Pl[h][l15 + 16][jo + 4];
            vb0.u[0] = *(const uint2*)&VT[h * DH + l15][jg];
            vb0.u[1] = *(const uint2*)&VT[h * DH + l15][jg + 4];
            vb1.u[0] = *(const uint2*)&VT[h * DH + 16 + l15][jg];
            vb1.u[1] = *(const uint2*)&VT[h * DH + 16 + l15][jg + 4];
            o[0][0] = __builtin_amdgcn_mfma_f32_16x16x32_bf16(pa0.v, vb0.v, o[0][0], 0, 0, 0);
            o[0][1] = __builtin_amdgcn_mfma_f32_16x16x32_bf16(pa0.v, vb1.v, o[0][1], 0, 0, 0);
            o[1][0] = __builtin_amdgcn_mfma_f32_16x16x32_bf16(pa1.v, vb0.v, o[1][0], 0, 0, 0);
            o[1][1] = __builtin_amdgcn_mfma_f32_16x16x32_bf16(pa1.v, vb1.v, o[1][1], 0, 0, 0);
        }
    }

    // ---- normalize + store (C-layout rows match inv[] rows exactly) ----
#pragma unroll
    for (int m = 0; m < 2; m++)
#pragma unroll
        for (int n = 0; n < 2; n++)
#pragma unroll
            for (int r = 0; r < 4; r++)
                og[((long long)b * NATOM + row0 + m * 16 + lg * 4 + r) * CA
                   + h * DH + n * 16 + l15]
                    = f2bf(o[m][n][r] * inv[m][r]);
}

// =====================================================================
// Final selector: write d_out as bf16 (flag=1) or f32 (flag=0)
// =====================================================================
__global__ __launch_bounds__(256) void select_kernel(
    const int* __restrict__ flag,
    const u16* __restrict__ outA, const u16* __restrict__ outB,
    void* __restrict__ d_out)
{
    const size_t i = (size_t)blockIdx.x * 256 + threadIdx.x;
    if (*flag) ((u16*)d_out)[i]   = outA[i];
    else       ((float*)d_out)[i] = bf2f(outB[i]);
}

// =====================================================================
// One full pipeline pass, templated on input storage type, gated on flag
// =====================================================================
template<typename TIN>
static void run_pass(void* const* d_in,
                     float* x, u16* h, u16* qb, u16* kb, u16* vb, u16* ob,
                     float* atok, u16* hidc, float* tbv, u16* outbuf,
                     const int* flag, int want, hipStream_t stream)
{
    const TIN* a    = (const TIN*)d_in[0];
    const int* idx  = (const int*)d_in[2];
    const TIN* W_a  = (const TIN*)d_in[3];
    const TIN* W_o  = (const TIN*)d_in[4];
    const TIN* Wcl  = (const TIN*)d_in[5];
    const TIN* Wcm  = (const TIN*)d_in[6];
    const TIN* Wm1  = (const TIN*)d_in[7];
    const TIN* Wm2  = (const TIN*)d_in[8];
    const TIN* Wpb  = (const TIN*)d_in[9];
    const TIN* Wq   = (const TIN*)d_in[10];
    const TIN* Wk   = (const TIN*)d_in[11];
    const TIN* Wv   = (const TIN*)d_in[12];
    const TIN* Wo   = (const TIN*)d_in[13];
    const TIN* ln1g = (const TIN*)d_in[14];
    const TIN* ln1b = (const TIN*)d_in[15];
    const TIN* Wt1  = (const TIN*)d_in[16];
    const TIN* Wt2  = (const TIN*)d_in[17];
    const TIN* ln2g = (const TIN*)d_in[18];
    const TIN* ln2b = (const TIN*)d_in[19];

    const size_t NEL = (size_t)BB * NATOM * CA;

    // token projection [8192 x 384] @ [384 x 128] -> f32 atok
    gemm128<TIN, TIN, false, false, false><<<64, 256, 0, stream>>>(
        flag, want, a, CTOK, W_a, CA, 0, atok, CA, 0, CTOK);
    gather_kernel<<<(unsigned)(NEL / 256), 256, 0, stream>>>(flag, want, atok, idx, x);
    bias_kernel<TIN><<<1, 512, 0, stream>>>(flag, want, x, Wcl, Wcm, Wm1, Wm2, Wpb, tbv);

    for (int l = 0; l < 3; l++) {
        const size_t wofs = (size_t)l * CA * CA;
        const size_t tofs = (size_t)l * CA * 512;   // same element count for Wt1/Wt2 blocks
        ln_kernel<TIN><<<BB * NATOM / 4, 256, 0, stream>>>(flag, want, x, ln1g + l * CA, ln1b + l * CA, h);
        gemm128<u16, TIN, true, false, false><<<512, 256, 0, stream>>>(flag, want, h, CA, Wq + wofs, CA, 0, qb, CA, 0, CA);
        gemm128<u16, TIN, true, false, false><<<512, 256, 0, stream>>>(flag, want, h, CA, Wk + wofs, CA, 0, kb, CA, 0, CA);
        gemm128<u16, TIN, true, false, false><<<512, 256, 0, stream>>>(flag, want, h, CA, Wv + wofs, CA, 0, vb, CA, 0, CA);
        attn_kernel<<<BB * NWIN, 256, 0, stream>>>(flag, want, qb, kb, vb, tbv, ob);
        gemm128<u16, TIN, false, true, false><<<512, 256, 0, stream>>>(flag, want, ob, CA, Wo + wofs, CA, 0, x, CA, 0, CA);
        ln_kernel<TIN><<<BB * NATOM / 4, 256, 0, stream>>>(flag, want, x, ln2g + l * CA, ln2b + l * CA, h);
        // MLP in 4 column chunks: x += relu(h @ Wt1[:,c*128..]) @ Wt2[c*128..,:]
        for (int c = 0; c < 4; c++) {
            gemm128<u16, TIN, true, false, true><<<512, 256, 0, stream>>>(
                flag, want, h, CA, Wt1 + tofs, 512, c * 128, hidc, CA, 0, CA);
            gemm128<u16, TIN, false, true, false><<<512, 256, 0, stream>>>(
                flag, want, hidc, CA, Wt2 + tofs + (size_t)c * 128 * CA, CA, 0, x, CA, 0, CA);
        }
    }
    // out = x @ W_out -> bf16 outbuf
    gemm128<float, TIN, true, false, false><<<512, 256, 0, stream>>>(
        flag, want, x, CA, W_o, CA, 0, outbuf, CA, 0, CA);
}

// =====================================================================
// Launch
// =====================================================================
extern "C" void kernel_launch(void* const* d_in, const int* in_sizes, int n_in,
                              void* d_out, int out_size, void* d_ws, size_t ws_size,
                              hipStream_t stream)
{
    (void)in_sizes; (void)n_in; (void)out_size;
    const size_t NEL = (size_t)BB * NATOM * CA;   // 8388608

    char* p = (char*)d_ws;
    float* x    = (float*)p;  p += NEL * 4;
    u16*   h    = (u16*)p;    p += NEL * 2;
    u16*   qb   = (u16*)p;    p += NEL * 2;
    u16*   kb   = (u16*)p;    p += NEL * 2;
    u16*   vb   = (u16*)p;    p += NEL * 2;
    u16*   ob   = (u16*)p;    p += NEL * 2;
    float* atok = (float*)p;  p += (size_t)BB * NTOK * CA * 4;
    u16*   hidc = (u16*)p;    p += NEL * 2;
    float* tbv  = (float*)p;  p += 8192;
    u16*   outA = (u16*)p;    p += NEL * 2;
    u16*   outB = (u16*)p;    p += NEL * 2;
    int*   flag = (int*)p;    p += 256;
    if ((size_t)(p - (char*)d_ws) > ws_size) return;  // workspace too small

    // 1) detect input storage dtype (writes flag: 1=bf16, 0=f32)
    detect_kernel<<<1, 256, 0, stream>>>((const u32*)d_in[3], flag);
    // 2) bf16-interpretation pass (runs only if flag==1)
    run_pass<u16>(d_in, x, h, qb, kb, vb, ob, atok, hidc, tbv, outA, flag, 1, stream);
    // 3) f32-interpretation pass (runs only if flag==0)
    run_pass<float>(d_in, x, h, qb, kb, vb, ob, atok, hidc, tbv, outB, flag, 0, stream);
    // 4) write d_out in the detected output format
    select_kernel<<<(unsigned)(NEL / 256), 256, 0, stream>>>(flag, outA, outB, d_out);
}

// Round 2
// 1253.577 us; speedup vs baseline: 2.3409x; 1.3002x over previous
//
#include <hip/hip_runtime.h>

typedef unsigned short u16;
typedef unsigned int   u32;

typedef __attribute__((ext_vector_type(8))) __bf16 bf16x8;
typedef __attribute__((ext_vector_type(4))) float  f32x4;

// ---------- scalar/vec conversion helpers ----------
__device__ __forceinline__ float bf2f(u16 v) {
    return __uint_as_float(((u32)v) << 16);
}
__device__ __forceinline__ u16 f2bf(float f) {
    u32 u = __float_as_uint(f);
    u32 r = (u + 0x7fffu + ((u >> 16) & 1u)) >> 16;  // round-to-nearest-even
    return (u16)r;
}
__device__ __forceinline__ void unpack8(uint4 u, float* f) {
    f[0] = __uint_as_float(u.x << 16); f[1] = __uint_as_float(u.x & 0xffff0000u);
    f[2] = __uint_as_float(u.y << 16); f[3] = __uint_as_float(u.y & 0xffff0000u);
    f[4] = __uint_as_float(u.z << 16); f[5] = __uint_as_float(u.z & 0xffff0000u);
    f[6] = __uint_as_float(u.w << 16); f[7] = __uint_as_float(u.w & 0xffff0000u);
}
// 16 contiguous elements -> float[16], overloaded on storage type
__device__ __forceinline__ void load16(const u16* p, float* f) {
    unpack8(*(const uint4*)p, f);
    unpack8(*(const uint4*)(p + 8), f + 8);
}
__device__ __forceinline__ void load16(const float* p, float* f) {
    const float4* q = (const float4*)p;
    float4 a = q[0], b = q[1], c = q[2], d = q[3];
    f[0]=a.x; f[1]=a.y; f[2]=a.z; f[3]=a.w;
    f[4]=b.x; f[5]=b.y; f[6]=b.z; f[7]=b.w;
    f[8]=c.x; f[9]=c.y; f[10]=c.z; f[11]=c.w;
    f[12]=d.x; f[13]=d.y; f[14]=d.z; f[15]=d.w;
}
__device__ __forceinline__ float ld1(const u16* p)   { return bf2f(*p); }
__device__ __forceinline__ float ld1(const float* p) { return *p; }

// ---------- problem constants ----------
#define BB 4
#define NTOK 2048
#define NATOM 16384
#define CTOK 384
#define CA 128
#define NQ 32
#define NK 128
#define NH 4
#define DH 32
#define NWIN 512
#define PAD 48

// Transposed-weight workspace layout (u16 elements).
// Each matrix stored as [N][K] hi-plane, then lo-plane (f32 path only).
#define WT_WA   0          // [128][384], plane 49152
#define WT_L0   98304      // per-layer block start
#define WT_LSZ  393216     // Q 0 | K 32768 | V 65536 | O 98304 | T1 131072 | T2 262144
#define WT_TOT  1277952    // 98304 + 3*393216

// =====================================================================
// dtype detector: look at low u16 of 1024 words of W_a.
// flag = 1 (bf16 inputs) or 0 (f32 inputs)
// =====================================================================
__global__ __launch_bounds__(256) void detect_kernel(const u32* __restrict__ wa,
                                                     int* __restrict__ flag)
{
    __shared__ int cnt;
    if (threadIdx.x == 0) cnt = 0;
    __syncthreads();
    int local = 0;
#pragma unroll
    for (int i = 0; i < 4; i++) {
        u32 w = wa[threadIdx.x * 4 + i];
        u32 e = (w >> 7) & 0xFFu;   // exponent field of the LOW u16 as bf16
        if (e >= 95u && e <= 135u) local++;
    }
    atomicAdd(&cnt, local);
    __syncthreads();
    if (threadIdx.x == 0) *flag = (cnt >= 614) ? 1 : 0;
}

// =====================================================================
// Scalar GEMM (kept for f32-A cases: token proj f32 path, final x@W_out)
// =====================================================================
#define GKC 32
#define GLDS 132

template<typename TA, typename TW, bool OUT_BF16, bool ADD, bool RELU>
__global__ __launch_bounds__(256) void gemm128(
    const int* __restrict__ flag, int want,
    const TA* __restrict__ A, int lda,
    const TW* __restrict__ W, int ldw, int wc0,
    void* __restrict__ Cv, int ldc, int cc0,
    int K)
{
    if (*flag != want) return;
    __shared__ float As[GKC][GLDS];   // [k][m]
    __shared__ float Ws[GKC][GLDS];   // [k][n]
    const int tid  = threadIdx.x;
    const int row0 = blockIdx.x * 128;
    const int cch  = blockIdx.y * 128;
    const int wcol = wc0 + cch;
    const int ccol = cc0 + cch;
    const int ty = tid >> 4, tx = tid & 15;

    float acc[8][8];
#pragma unroll
    for (int i = 0; i < 8; i++)
#pragma unroll
        for (int j = 0; j < 8; j++) acc[i][j] = 0.f;

    const int m_l = tid >> 1;          // 0..127
    const int ak0 = (tid & 1) << 4;    // 0 / 16
    const int w_k = tid >> 3;          // 0..31
    const int wcc = (tid & 7) << 4;    // 0..112

    for (int kc = 0; kc < K; kc += GKC) {
        float av16[16], wv16[16];
        load16(A + (size_t)(row0 + m_l) * lda + kc + ak0, av16);
        load16(W + (size_t)(kc + w_k) * ldw + wcol + wcc, wv16);
        __syncthreads();   // previous iteration's compute done
#pragma unroll
        for (int j = 0; j < 16; j++) As[ak0 + j][m_l] = av16[j];
#pragma unroll
        for (int j = 0; j < 16; j++) Ws[w_k][wcc + j] = wv16[j];
        __syncthreads();

        for (int k = 0; k < GKC; k++) {
            const float4 a0 = *(const float4*)&As[k][ty << 3];
            const float4 a1 = *(const float4*)&As[k][(ty << 3) + 4];
            const float4 w0 = *(const float4*)&Ws[k][tx << 3];
            const float4 w1 = *(const float4*)&Ws[k][(tx << 3) + 4];
            const float a[8]  = {a0.x, a0.y, a0.z, a0.w, a1.x, a1.y, a1.z, a1.w};
            const float wv[8] = {w0.x, w0.y, w0.z, w0.w, w1.x, w1.y, w1.z, w1.w};
#pragma unroll
            for (int i = 0; i < 8; i++)
#pragma unroll
                for (int j = 0; j < 8; j++)
                    acc[i][j] = fmaf(a[i], wv[j], acc[i][j]);
        }
    }

#pragma unroll
    for (int i = 0; i < 8; i++) {
        const size_t r = (size_t)row0 + (ty << 3) + i;
        if (OUT_BF16) {
            union { u16 s[8]; uint4 v; } pk;
#pragma unroll
            for (int j = 0; j < 8; j++) {
                float v = acc[i][j];
                if (RELU) v = fmaxf(v, 0.f);
                pk.s[j] = f2bf(v);
            }
            *(uint4*)((u16*)Cv + r * ldc + ccol + (tx << 3)) = pk.v;
        } else {
            float* C = (float*)Cv + r * ldc + ccol + (tx << 3);
            float4 c0, c1;
            if (ADD) { c0 = ((const float4*)C)[0]; c1 = ((const float4*)C)[1]; }
            else     { c0 = make_float4(0,0,0,0);  c1 = make_float4(0,0,0,0); }
            c0.x += acc[i][0]; c0.y += acc[i][1]; c0.z += acc[i][2]; c0.w += acc[i][3];
            c1.x += acc[i][4]; c1.y += acc[i][5]; c1.z += acc[i][6]; c1.w += acc[i][7];
            ((float4*)C)[0] = c0; ((float4*)C)[1] = c1;
        }
    }
}

// =====================================================================
// Weight transpose (+ bf16 split for f32 inputs) into WT workspace.
// 39 tiles of 128x128: Wa(3) | Wq/k/v/o x3 layers (12) | Wt1 (12) | Wt2 (12)
// dst[n][k] = src[k][n]; f32 path: hi = bf16(w), lo = bf16(w - hi).
// =====================================================================
template<typename TIN, int SPLIT>
__global__ __launch_bounds__(256) void wtrans_kernel(
    const int* __restrict__ flag, int want,
    const TIN* __restrict__ Wa, const TIN* __restrict__ Wq,
    const TIN* __restrict__ Wk, const TIN* __restrict__ Wv,
    const TIN* __restrict__ Wo, const TIN* __restrict__ Wt1,
    const TIN* __restrict__ Wt2, u16* __restrict__ WT)
{
    if (*flag != want) return;
    const int t = blockIdx.x;
    const TIN* S; int sld; u16* D; int dld; int plane;
    if (t < 3) {                                     // W_a [384][128]
        S = Wa + t * 128 * 128; sld = 128;
        D = WT + WT_WA + t * 128; dld = 384; plane = 49152;
    } else if (t < 15) {                             // Wq/k/v/o [128][128]
        const int i = t - 3, l = i >> 2, m = i & 3;
        const TIN* ms = (m == 0) ? Wq : (m == 1) ? Wk : (m == 2) ? Wv : Wo;
        S = ms + l * 16384; sld = 128;
        D = WT + WT_L0 + l * WT_LSZ + m * 32768; dld = 128; plane = 16384;
    } else if (t < 27) {                             // Wt1 [128][512] col-chunk c
        const int i = t - 15, l = i >> 2, c = i & 3;
        S = Wt1 + l * 65536 + c * 128; sld = 512;
        D = WT + WT_L0 + l * WT_LSZ + 131072 + c * 128 * 128; dld = 128; plane = 65536;
    } else {                                         // Wt2 [512][128] row-chunk c
        const int i = t - 27, l = i >> 2, c = i & 3;
        S = Wt2 + l * 65536 + c * 128 * 128; sld = 128;
        D = WT + WT_L0 + l * WT_LSZ + 262144 + c * 128; dld = 512; plane = 65536;
    }
    const int tid = threadIdx.x;
    for (int id = tid; id < 2048; id += 256) {
        const int n = id >> 4, k0 = (id & 15) << 3;
        union { u16 s[8]; uint4 v; } hi, lo;
#pragma unroll
        for (int j = 0; j < 8; j++) {
            if constexpr (sizeof(TIN) == 2) {
                hi.s[j] = ((const u16*)(const void*)S)[(k0 + j) * sld + n];
                lo.s[j] = 0;
            } else {
                const float v = ((const float*)(const void*)S)[(k0 + j) * sld + n];
                const u16 hv = f2bf(v);
                hi.s[j] = hv;
                lo.s[j] = f2bf(v - bf2f(hv));
            }
        }
        *(uint4*)(D + n * dld + k0) = hi.v;
        if (SPLIT == 2) *(uint4*)(D + plane + n * dld + k0) = lo.v;
    }
}

// =====================================================================
// MFMA GEMM: C[M x 128] = A[M x K](bf16) @ W[K x 128] using WT [128][K].
// grid.x = M/128; 4 waves x (32 rows x 128 cols); no LDS, no barriers.
// NSPLIT=2 adds the lo-plane MFMA (f32 weights split into hi+lo bf16).
// =====================================================================
template<int NSPLIT, int K, bool OUT_BF16, bool ADD>
__global__ __launch_bounds__(256) void mgemm(
    const int* __restrict__ flag, int want,
    const u16* __restrict__ A, int lda,
    const u16* __restrict__ WT, int ldk,
    void* __restrict__ Cv, int ldc)
{
    if (*flag != want) return;
    const int tid  = threadIdx.x;
    const int lane = tid & 63, wv = tid >> 6;
    const int l15  = lane & 15, lg = lane >> 4;
    const long long row0 = (long long)blockIdx.x * 128 + wv * 32;
    const int plane = ldk << 7;   // 128 * ldk

    f32x4 acc[2][8];
    {
        f32x4 z = {0.f, 0.f, 0.f, 0.f};
#pragma unroll
        for (int m = 0; m < 2; m++)
#pragma unroll
            for (int n = 0; n < 8; n++) acc[m][n] = z;
    }

    const u16* A0 = A + (row0 + l15) * (long long)lda + lg * 8;
    const u16* A1 = A0 + 16LL * lda;
    const u16* W0 = WT + (long long)l15 * ldk + lg * 8;

    for (int kk = 0; kk < K; kk += 32) {
        const bf16x8 a0 = *(const bf16x8*)(A0 + kk);
        const bf16x8 a1 = *(const bf16x8*)(A1 + kk);
#pragma unroll
        for (int n = 0; n < 8; n++) {
            const bf16x8 b = *(const bf16x8*)(W0 + n * 16 * ldk + kk);
            acc[0][n] = __builtin_amdgcn_mfma_f32_16x16x32_bf16(a0, b, acc[0][n], 0, 0, 0);
            acc[1][n] = __builtin_amdgcn_mfma_f32_16x16x32_bf16(a1, b, acc[1][n], 0, 0, 0);
            if (NSPLIT == 2) {
                const bf16x8 bl = *(const bf16x8*)(W0 + plane + n * 16 * ldk + kk);
                acc[0][n] = __builtin_amdgcn_mfma_f32_16x16x32_bf16(a0, bl, acc[0][n], 0, 0, 0);
                acc[1][n] = __builtin_amdgcn_mfma_f32_16x16x32_bf16(a1, bl, acc[1][n], 0, 0, 0);
            }
        }
    }

#pragma unroll
    for (int m = 0; m < 2; m++)
#pragma unroll
        for (int r = 0; r < 4; r++) {
            const long long row = row0 + m * 16 + lg * 4 + r;
            if (OUT_BF16) {
                u16* C = (u16*)Cv + row * ldc;
#pragma unroll
                for (int n = 0; n < 8; n++) C[n * 16 + l15] = f2bf(acc[m][n][r]);
            } else {
                float* C = (float*)Cv + row * ldc;
#pragma unroll
                for (int n = 0; n < 8; n++) {
                    float v = acc[m][n][r];
                    if (ADD) v += C[n * 16 + l15];
                    C[n * 16 + l15] = v;
                }
            }
        }
}

// =====================================================================
// Fused MLP: x += relu(h @ Wt1) @ Wt2, looping the 4 hidden chunks
// in-register. Hidden (bf16-rounded, same as old hidc) round-trips via
// per-wave LDS (same trick as attn's P). No __syncthreads.
// W1T [512][128] (lo at +65536); W2T [128][512] (lo at +65536).
// =====================================================================
template<int NSPLIT>
__global__ __launch_bounds__(256) void mlp_fused(
    const int* __restrict__ flag, int want,
    const u16* __restrict__ h,
    const u16* __restrict__ W1T, const u16* __restrict__ W2T,
    float* __restrict__ x)
{
    if (*flag != want) return;
    __shared__ __align__(16) u16 Pl[4][32][132];
    const int tid  = threadIdx.x;
    const int lane = tid & 63, wv = tid >> 6;
    const int l15  = lane & 15, lg = lane >> 4;
    const long long row0 = (long long)blockIdx.x * 128 + wv * 32;

    bf16x8 ah[2][4];
#pragma unroll
    for (int m = 0; m < 2; m++)
#pragma unroll
        for (int kk = 0; kk < 4; kk++)
            ah[m][kk] = *(const bf16x8*)(h + (row0 + m * 16 + l15) * 128 + kk * 32 + lg * 8);

    f32x4 xacc[2][8];
    {
        f32x4 z = {0.f, 0.f, 0.f, 0.f};
#pragma unroll
        for (int m = 0; m < 2; m++)
#pragma unroll
            for (int n = 0; n < 8; n++) xacc[m][n] = z;
    }

    for (int c = 0; c < 4; c++) {
        f32x4 hacc[2][8];
        {
            f32x4 z = {0.f, 0.f, 0.f, 0.f};
#pragma unroll
            for (int m = 0; m < 2; m++)
#pragma unroll
                for (int n = 0; n < 8; n++) hacc[m][n] = z;
        }
#pragma unroll
        for (int kk = 0; kk < 4; kk++) {
#pragma unroll
            for (int n = 0; n < 8; n++) {
                const u16* wp = W1T + (c * 128 + n * 16 + l15) * 128 + kk * 32 + lg * 8;
                const bf16x8 b = *(const bf16x8*)wp;
                hacc[0][n] = __builtin_amdgcn_mfma_f32_16x16x32_bf16(ah[0][kk], b, hacc[0][n], 0, 0, 0);
                hacc[1][n] = __builtin_amdgcn_mfma_f32_16x16x32_bf16(ah[1][kk], b, hacc[1][n], 0, 0, 0);
                if (NSPLIT == 2) {
                    const bf16x8 bl = *(const bf16x8*)(wp + 65536);
                    hacc[0][n] = __builtin_amdgcn_mfma_f32_16x16x32_bf16(ah[0][kk], bl, hacc[0][n], 0, 0, 0);
                    hacc[1][n] = __builtin_amdgcn_mfma_f32_16x16x32_bf16(ah[1][kk], bl, hacc[1][n], 0, 0, 0);
                }
            }
        }
        // relu + bf16 -> per-wave LDS (WAR: drain prior chunk's reads first)
        asm volatile("s_waitcnt lgkmcnt(0)" ::: "memory");
#pragma unroll
        for (int m = 0; m < 2; m++)
#pragma unroll
            for (int n = 0; n < 8; n++)
#pragma unroll
                for (int r = 0; r < 4; r++)
                    Pl[wv][m * 16 + lg * 4 + r][n * 16 + l15]
                        = f2bf(fmaxf(hacc[m][n][r], 0.f));
        asm volatile("s_waitcnt lgkmcnt(0)" ::: "memory");

        bf16x8 a2[2][4];
#pragma unroll
        for (int m = 0; m < 2; m++)
#pragma unroll
            for (int kk = 0; kk < 4; kk++) {
                union { uint2 u[2]; bf16x8 v; } tmp;
                tmp.u[0] = *(const uint2*)&Pl[wv][m * 16 + l15][kk * 32 + lg * 8];
                tmp.u[1] = *(const uint2*)&Pl[wv][m * 16 + l15][kk * 32 + lg * 8 + 4];
                a2[m][kk] = tmp.v;
            }
#pragma unroll
        for (int kk = 0; kk < 4; kk++) {
#pragma unroll
            for (int n = 0; n < 8; n++) {
                const u16* wp = W2T + (n * 16 + l15) * 512 + c * 128 + kk * 32 + lg * 8;
                const bf16x8 b = *(const bf16x8*)wp;
                xacc[0][n] = __builtin_amdgcn_mfma_f32_16x16x32_bf16(a2[0][kk], b, xacc[0][n], 0, 0, 0);
                xacc[1][n] = __builtin_amdgcn_mfma_f32_16x16x32_bf16(a2[1][kk], b, xacc[1][n], 0, 0, 0);
                if (NSPLIT == 2) {
                    const bf16x8 bl = *(const bf16x8*)(wp + 65536);
                    xacc[0][n] = __builtin_amdgcn_mfma_f32_16x16x32_bf16(a2[0][kk], bl, xacc[0][n], 0, 0, 0);
                    xacc[1][n] = __builtin_amdgcn_mfma_f32_16x16x32_bf16(a2[1][kk], bl, xacc[1][n], 0, 0, 0);
                }
            }
        }
    }

#pragma unroll
    for (int m = 0; m < 2; m++)
#pragma unroll
        for (int r = 0; r < 4; r++) {
            float* X = x + (row0 + m * 16 + lg * 4 + r) * 128;
#pragma unroll
            for (int n = 0; n < 8; n++) X[n * 16 + l15] += xacc[m][n][r];
        }
}

// =====================================================================
// Gather: x[b,n,:] = a_tok[b, idx[b,n], :]   (f32 -> f32)
// =====================================================================
__global__ __launch_bounds__(256) void gather_kernel(
    const int* __restrict__ flag, int want,
    const float* __restrict__ a_tok, const int* __restrict__ idx,
    float* __restrict__ x)
{
    if (*flag != want) return;
    const size_t i = (size_t)blockIdx.x * 256 + threadIdx.x;  // B*N*128 total
    const int c = (int)(i & 127);
    const size_t an = i >> 7;
    const int b = (int)(an >> 14);
    const int n = (int)(an & (NATOM - 1));
    const int t = idx[b * NATOM + n];
    x[i] = a_tok[(((size_t)b * NTOK) + t) * CA + c];
}

// =====================================================================
// LayerNorm: h = (x-m)*rsqrt(var+1e-5)*g + b   (f32 in, bf16 out)
// =====================================================================
template<typename TW>
__global__ __launch_bounds__(256) void ln_kernel(
    const int* __restrict__ flag, int want,
    const float* __restrict__ x, const TW* __restrict__ g,
    const TW* __restrict__ b, u16* __restrict__ h)
{
    if (*flag != want) return;
    const int lane = threadIdx.x & 63;
    const int wv   = threadIdx.x >> 6;
    const size_t atom = (size_t)blockIdx.x * 4 + wv;
    const float* xr = x + atom * CA;
    const float v0 = xr[lane], v1 = xr[lane + 64];
    float s  = v0 + v1;
    float sq = v0 * v0 + v1 * v1;
#pragma unroll
    for (int off = 32; off > 0; off >>= 1) {
        s  += __shfl_xor(s,  off, 64);
        sq += __shfl_xor(sq, off, 64);
    }
    const float mean = s * 0.0078125f;
    const float var  = sq * 0.0078125f - mean * mean;
    const float inv  = rsqrtf(var + 1e-5f);
    u16* hr = h + atom * CA;
    hr[lane]      = f2bf((v0 - mean) * inv * ld1(g + lane)      + ld1(b + lane));
    hr[lane + 64] = f2bf((v1 - mean) * inv * ld1(g + lane + 64) + ld1(b + lane + 64));
}

// =====================================================================
// Bias: t[b,a,h] for a < 128 from the pair-MLP; single block, 512 threads
// =====================================================================
template<typename TW>
__global__ __launch_bounds__(512) void bias_kernel(
    const int* __restrict__ flag, int want,
    const float* __restrict__ x,
    const TW* __restrict__ Wcl, const TW* __restrict__ Wcm,
    const TW* __restrict__ Wm1, const TW* __restrict__ Wm2,
    const TW* __restrict__ Wpb, float* __restrict__ tb)
{
    if (*flag != want) return;
    __shared__ float Wsum[128][16];
    __shared__ float M1[16][16];
    __shared__ float M2[16][16];
    __shared__ float Pb[16][4];
    const int tid = threadIdx.x;
    for (int i = tid; i < 128 * 16; i += 512)
        Wsum[i >> 4][i & 15] = ld1(Wcl + i) + ld1(Wcm + i);
    if (tid < 256) M1[tid >> 4][tid & 15] = ld1(Wm1 + tid);
    if (tid >= 256 && tid < 512) { int t2 = tid - 256; M2[t2 >> 4][t2 & 15] = ld1(Wm2 + t2); }
    if (tid < 64) Pb[tid >> 2][tid & 3] = ld1(Wpb + tid);
    __syncthreads();

    const int b = tid >> 7, a = tid & 127;
    const float* xa = x + ((size_t)b * NATOM + a) * CA;
    float u[16];
#pragma unroll
    for (int p = 0; p < 16; p++) u[p] = 0.f;
    for (int c = 0; c < 128; c++) {
        const float xv = xa[c];
#pragma unroll
        for (int p = 0; p < 16; p++) u[p] = fmaf(xv, Wsum[c][p], u[p]);
    }
    float r1[16];
#pragma unroll
    for (int p = 0; p < 16; p++) r1[p] = 0.f;
    for (int c = 0; c < 16; c++) {
        const float rv = fmaxf(u[c], 0.f);
#pragma unroll
        for (int p = 0; p < 16; p++) r1[p] = fmaf(rv, M1[c][p], r1[p]);
    }
    float r2[16];
#pragma unroll
    for (int p = 0; p < 16; p++) r2[p] = 0.f;
    for (int c = 0; c < 16; c++) {
        const float rv = fmaxf(r1[c], 0.f);
#pragma unroll
        for (int p = 0; p < 16; p++) r2[p] = fmaf(rv, M2[c][p], r2[p]);
    }
#pragma unroll
    for (int hh = 0; hh < 4; hh++) {
        float s = 0.f;
#pragma unroll
        for (int p = 0; p < 16; p++) s = fmaf(r2[p], Pb[p][hh], s);
        tb[(size_t)tid * 4 + hh] = s;
    }
}

// =====================================================================
// Windowed attention via MFMA (verified round 1): one block per (b, w).
// =====================================================================
#define VTP 132   // V^T row stride in u16
#define PPS 68    // P row stride in u16

__global__ __launch_bounds__(256) void attn_kernel(
    const int* __restrict__ flag, int want,
    const u16* __restrict__ qg, const u16* __restrict__ kg,
    const u16* __restrict__ vg, const float* __restrict__ tb,
    u16* __restrict__ og)
{
    if (*flag != want) return;
    __shared__ __align__(16) u16 VT[128][VTP];    // V^T: [d][j]
    __shared__ __align__(16) u16 Pl[NH][32][PPS]; // per-head P half

    const int tid  = threadIdx.x;
    const int lane = tid & 63;
    const int h    = tid >> 6;             // wave id == head
    const int b    = blockIdx.x >> 9;
    const int w    = blockIdx.x & (NWIN - 1);
    const int row0 = w * NQ;
    const int kbase = row0 - PAD;          // first key atom (may be < 0)
    const int l15 = lane & 15;
    const int lg  = lane >> 4;

    // ---- stage V^T into LDS (all 256 threads; zero invalid rows) ----
    {
        const int j  = tid & 127;
        const int d0 = (tid >> 7) << 6;    // 0 or 64
        const int ga = kbase + j;
        const bool val = (ga >= 0) && (ga < NATOM);
        const u16* vrow = vg + ((long long)b * NATOM + ga) * CA + d0;
#pragma unroll
        for (int t2 = 0; t2 < 8; t2++) {
            union { uint4 q; u16 s[8]; } u;
            if (val) u.q = *(const uint4*)(vrow + t2 * 8);
            else     u.q = make_uint4(0u, 0u, 0u, 0u);
#pragma unroll
            for (int e = 0; e < 8; e++) VT[d0 + t2 * 8 + e][j] = u.s[e];
        }
    }

    // ---- QK^T: S[32][128] per head, frags direct from global ----
    const long long qoff = ((long long)b * NATOM + row0) * CA + h * DH;
    const long long koff = ((long long)b * NATOM + kbase) * CA + h * DH;
    bf16x8 aq0 = *(const bf16x8*)(qg + qoff + (long long)l15 * CA + lg * 8);
    bf16x8 aq1 = *(const bf16x8*)(qg + qoff + (long long)(l15 + 16) * CA + lg * 8);

    f32x4 acc[2][8];
    {
        f32x4 z = {0.f, 0.f, 0.f, 0.f};
#pragma unroll
        for (int m = 0; m < 2; m++)
#pragma unroll
            for (int n = 0; n < 8; n++) acc[m][n] = z;
    }
#pragma unroll
    for (int n = 0; n < 8; n++) {
        bf16x8 bk = *(const bf16x8*)(kg + koff + (long long)(n * 16 + l15) * CA + lg * 8);
        acc[0][n] = __builtin_amdgcn_mfma_f32_16x16x32_bf16(aq0, bk, acc[0][n], 0, 0, 0);
        acc[1][n] = __builtin_amdgcn_mfma_f32_16x16x32_bf16(aq1, bk, acc[1][n], 0, 0, 0);
    }

    // ---- bias + scale + mask ----
    const float scale = 0.17677669529663687f;  // 1/sqrt(32)
    float tj[8], ti[2][4];
#pragma unroll
    for (int n = 0; n < 8; n++)
        tj[n] = tb[((size_t)b * 128 + n * 16 + l15) * 4 + h];
#pragma unroll
    for (int m = 0; m < 2; m++)
#pragma unroll
        for (int r = 0; r < 4; r++)
            ti[m][r] = tb[((size_t)b * 128 + m * 16 + lg * 4 + r) * 4 + h];

#pragma unroll
    for (int n = 0; n < 8; n++) {
        const int ga = kbase + n * 16 + l15;
        const bool val = (ga >= 0) && (ga < NATOM);
#pragma unroll
        for (int m = 0; m < 2; m++)
#pragma unroll
            for (int r = 0; r < 4; r++) {
                const float s = acc[m][n][r] * scale + ti[m][r] + tj[n];
                acc[m][n][r] = val ? s : -1e9f;
            }
    }

    // ---- softmax ----
    float mx[2][4], inv[2][4];
#pragma unroll
    for (int m = 0; m < 2; m++)
#pragma unroll
        for (int r = 0; r < 4; r++) {
            float v = acc[m][0][r];
#pragma unroll
            for (int n = 1; n < 8; n++) v = fmaxf(v, acc[m][n][r]);
            v = fmaxf(v, __shfl_xor(v, 1, 64));
            v = fmaxf(v, __shfl_xor(v, 2, 64));
            v = fmaxf(v, __shfl_xor(v, 4, 64));
            v = fmaxf(v, __shfl_xor(v, 8, 64));
            mx[m][r] = v;
        }
#pragma unroll
    for (int m = 0; m < 2; m++)
#pragma unroll
        for (int n = 0; n < 8; n++)
#pragma unroll
            for (int r = 0; r < 4; r++)
                acc[m][n][r] = __expf(acc[m][n][r] - mx[m][r]);
#pragma unroll
    for (int m = 0; m < 2; m++)
#pragma unroll
        for (int r = 0; r < 4; r++) {
            float v = 0.f;
#pragma unroll
            for (int n = 0; n < 8; n++) v += acc[m][n][r];
            v += __shfl_xor(v, 1, 64);
            v += __shfl_xor(v, 2, 64);
            v += __shfl_xor(v, 4, 64);
            v += __shfl_xor(v, 8, 64);
            inv[m][r] = 1.0f / v;
        }

    __syncthreads();   // V^T staged

    // ---- PV ----
    f32x4 o[2][2];
    {
        f32x4 z = {0.f, 0.f, 0.f, 0.f};
        o[0][0] = z; o[0][1] = z; o[1][0] = z; o[1][1] = z;
    }
    union B8 { bf16x8 v; uint2 u[2]; };
#pragma unroll
    for (int half = 0; half < 2; half++) {
        asm volatile("s_waitcnt lgkmcnt(0)" ::: "memory");
#pragma unroll
        for (int m = 0; m < 2; m++)
#pragma unroll
            for (int nn = 0; nn < 4; nn++)
#pragma unroll
                for (int r = 0; r < 4; r++)
                    Pl[h][m * 16 + lg * 4 + r][nn * 16 + l15]
                        = f2bf(acc[m][half * 4 + nn][r]);
        asm volatile("s_waitcnt lgkmcnt(0)" ::: "memory");
#pragma unroll
        for (int ks2 = 0; ks2 < 2; ks2++) {
            const int jo = ks2 * 32 + lg * 8;
            const int jg = half * 64 + jo;
            B8 pa0, pa1, vb0, vb1;
            pa0.u[0] = *(const uint2*)&Pl[h][l15][jo];
            pa0.u[1] = *(const uint2*)&Pl[h][l15][jo + 4];
            pa1.u[0] = *(const uint2*)&Pl[h][l15 + 16][jo];
            pa1.u[1] = *(const uint2*)&Pl[h][l15 + 16][jo + 4];
            vb0.u[0] = *(const uint2*)&VT[h * DH + l15][jg];
            vb0.u[1] = *(const uint2*)&VT[h * DH + l15][jg + 4];
            vb1.u[0] = *(const uint2*)&VT[h * DH + 16 + l15][jg];
            vb1.u[1] = *(const uint2*)&VT[h * DH + 16 + l15][jg + 4];
            o[0][0] = __builtin_amdgcn_mfma_f32_16x16x32_bf16(pa0.v, vb0.v, o[0][0], 0, 0, 0);
            o[0][1] = __builtin_amdgcn_mfma_f32_16x16x32_bf16(pa0.v, vb1.v, o[0][1], 0, 0, 0);
            o[1][0] = __builtin_amdgcn_mfma_f32_16x16x32_bf16(pa1.v, vb0.v, o[1][0], 0, 0, 0);
            o[1][1] = __builtin_amdgcn_mfma_f32_16x16x32_bf16(pa1.v, vb1.v, o[1][1], 0, 0, 0);
        }
    }

#pragma unroll
    for (int m = 0; m < 2; m++)
#pragma unroll
        for (int n = 0; n < 2; n++)
#pragma unroll
            for (int r = 0; r < 4; r++)
                og[((long long)b * NATOM + row0 + m * 16 + lg * 4 + r) * CA
                   + h * DH + n * 16 + l15]
                    = f2bf(o[m][n][r] * inv[m][r]);
}

// =====================================================================
// Final selector: write d_out as bf16 (flag=1) or f32 (flag=0)
// =====================================================================
__global__ __launch_bounds__(256) void select_kernel(
    const int* __restrict__ flag,
    const u16* __restrict__ outA, const u16* __restrict__ outB,
    void* __restrict__ d_out)
{
    const size_t i = (size_t)blockIdx.x * 256 + threadIdx.x;
    if (*flag) ((u16*)d_out)[i]   = outA[i];
    else       ((float*)d_out)[i] = bf2f(outB[i]);
}

// =====================================================================
// One full pipeline pass, templated on input storage type, gated on flag
// =====================================================================
template<typename TIN>
static void run_pass(void* const* d_in,
                     float* x, u16* h, u16* qb, u16* kb, u16* vb, u16* ob,
                     float* atok, u16* wt, float* tbv, u16* outbuf,
                     const int* flag, int want, hipStream_t stream)
{
    constexpr int NS = (sizeof(TIN) == 2) ? 1 : 2;

    const TIN* a    = (const TIN*)d_in[0];
    const int* idx  = (const int*)d_in[2];
    const TIN* W_a  = (const TIN*)d_in[3];
    const TIN* W_o  = (const TIN*)d_in[4];
    const TIN* Wcl  = (const TIN*)d_in[5];
    const TIN* Wcm  = (const TIN*)d_in[6];
    const TIN* Wm1  = (const TIN*)d_in[7];
    const TIN* Wm2  = (const TIN*)d_in[8];
    const TIN* Wpb  = (const TIN*)d_in[9];
    const TIN* Wq   = (const TIN*)d_in[10];
    const TIN* Wk   = (const TIN*)d_in[11];
    const TIN* Wv   = (const TIN*)d_in[12];
    const TIN* Wo   = (const TIN*)d_in[13];
    const TIN* ln1g = (const TIN*)d_in[14];
    const TIN* ln1b = (const TIN*)d_in[15];
    const TIN* Wt1  = (const TIN*)d_in[16];
    const TIN* Wt2  = (const TIN*)d_in[17];
    const TIN* ln2g = (const TIN*)d_in[18];
    const TIN* ln2b = (const TIN*)d_in[19];

    const size_t NEL = (size_t)BB * NATOM * CA;

    // 0) transpose (+split) all weights into WT workspace
    wtrans_kernel<TIN, NS><<<39, 256, 0, stream>>>(
        flag, want, W_a, Wq, Wk, Wv, Wo, Wt1, Wt2, wt);

    // 1) token projection [8192 x 384] @ [384 x 128] -> f32 atok
    if constexpr (NS == 1)
        mgemm<1, CTOK, false, false><<<BB * NTOK / 128, 256, 0, stream>>>(
            flag, want, (const u16*)a, CTOK, wt + WT_WA, CTOK, atok, CA);
    else
        gemm128<float, float, false, false, false><<<64, 256, 0, stream>>>(
            flag, want, (const float*)a, CTOK, (const float*)W_a, CA, 0, atok, CA, 0, CTOK);

    gather_kernel<<<(unsigned)(NEL / 256), 256, 0, stream>>>(flag, want, atok, idx, x);
    bias_kernel<TIN><<<1, 512, 0, stream>>>(flag, want, x, Wcl, Wcm, Wm1, Wm2, Wpb, tbv);

    for (int l = 0; l < 3; l++) {
        u16* wl = wt + WT_L0 + (size_t)l * WT_LSZ;
        ln_kernel<TIN><<<BB * NATOM / 4, 256, 0, stream>>>(flag, want, x, ln1g + l * CA, ln1b + l * CA, h);
        mgemm<NS, CA, true, false><<<512, 256, 0, stream>>>(flag, want, h, CA, wl,          CA, qb, CA);
        mgemm<NS, CA, true, false><<<512, 256, 0, stream>>>(flag, want, h, CA, wl + 32768,  CA, kb, CA);
        mgemm<NS, CA, true, false><<<512, 256, 0, stream>>>(flag, want, h, CA, wl + 65536,  CA, vb, CA);
        attn_kernel<<<BB * NWIN, 256, 0, stream>>>(flag, want, qb, kb, vb, tbv, ob);
        mgemm<NS, CA, false, true><<<512, 256, 0, stream>>>(flag, want, ob, CA, wl + 98304, CA, x, CA);
        ln_kernel<TIN><<<BB * NATOM / 4, 256, 0, stream>>>(flag, want, x, ln2g + l * CA, ln2b + l * CA, h);
        mlp_fused<NS><<<512, 256, 0, stream>>>(flag, want, h, wl + 131072, wl + 262144, x);
    }
    // out = x @ W_out -> bf16 outbuf (A is f32 residual: keep scalar path)
    gemm128<float, TIN, true, false, false><<<512, 256, 0, stream>>>(
        flag, want, x, CA, W_o, CA, 0, outbuf, CA, 0, CA);
}

// =====================================================================
// Launch
// =====================================================================
extern "C" void kernel_launch(void* const* d_in, const int* in_sizes, int n_in,
                              void* d_out, int out_size, void* d_ws, size_t ws_size,
                              hipStream_t stream)
{
    (void)in_sizes; (void)n_in; (void)out_size;
    const size_t NEL = (size_t)BB * NATOM * CA;   // 8388608

    char* p = (char*)d_ws;
    float* x    = (float*)p;  p += NEL * 4;
    u16*   h    = (u16*)p;    p += NEL * 2;
    u16*   qb   = (u16*)p;    p += NEL * 2;
    u16*   kb   = (u16*)p;    p += NEL * 2;
    u16*   vb   = (u16*)p;    p += NEL * 2;
    u16*   ob   = (u16*)p;    p += NEL * 2;
    float* atok = (float*)p;  p += (size_t)BB * NTOK * CA * 4;
    float* tbv  = (float*)p;  p += 8192;
    u16*   outA = (u16*)p;    p += NEL * 2;
    u16*   outB = (u16*)p;    p += NEL * 2;
    int*   flag = (int*)p;    p += 256;
    u16*   wt   = (u16*)p;    p += (size_t)WT_TOT * 2;
    if ((size_t)(p - (char*)d_ws) > ws_size) return;  // workspace too small

    // 1) detect input storage dtype (writes flag: 1=bf16, 0=f32)
    detect_kernel<<<1, 256, 0, stream>>>((const u32*)d_in[3], flag);
    // 2) bf16-interpretation pass (runs only if flag==1)
    run_pass<u16>(d_in, x, h, qb, kb, vb, ob, atok, wt, tbv, outA, flag, 1, stream);
    // 3) f32-interpretation pass (runs only if flag==0)
    run_pass<float>(d_in, x, h, qb, kb, vb, ob, atok, wt, tbv, outB, flag, 0, stream);
    // 4) write d_out in the detected output format
    select_kernel<<<(unsigned)(NEL / 256), 256, 0, stream>>>(flag, outA, outB, d_out);
}